// Round 2
// baseline (2821.156 us; speedup 1.0000x reference)
//
#include <hip/hip_runtime.h>

// MetaMultiParallelMLP: G=16 groups, D=8 hidden layers, W=64, IN_CH=3, OUT_CH=4,
// skip-concat of x after layer 4 (layer 5 has ci=67). B=1, N=65536. All fp32.
//
// Baseline strategy: one thread = one point. Activations live in registers
// (fully unrolled loops -> static indexing). Weights are uniform per block
// (group index from blockIdx.y) -> scalar loads (s_load) on the scalar pipe,
// FMAs on the vector pipe. Outputs written as float4.

#define NG 16
#define NPTS 65536
#define WID 64
#define IN_CH 3
#define OUT_CH 4

__device__ __forceinline__ void dense64_relu(const float* __restrict__ wp,
                                             const float* __restrict__ bp,
                                             const float* __restrict__ hin,
                                             float* __restrict__ hout) {
  // hout[o] = relu(bp[o] + sum_c wp[o*64+c] * hin[c])
  #pragma unroll
  for (int o = 0; o < 64; ++o) {
    float acc = bp[o];
    #pragma unroll
    for (int c = 0; c < 64; ++c) acc = fmaf(wp[o * 64 + c], hin[c], acc);
    hout[o] = fmaxf(acc, 0.0f);
  }
}

__global__ __launch_bounds__(256) void mlp_fused_kernel(
    const float* __restrict__ x,
    const float* __restrict__ w0, const float* __restrict__ b0,
    const float* __restrict__ w1, const float* __restrict__ b1,
    const float* __restrict__ w2, const float* __restrict__ b2,
    const float* __restrict__ w3, const float* __restrict__ b3,
    const float* __restrict__ w4, const float* __restrict__ b4,
    const float* __restrict__ w5, const float* __restrict__ b5,
    const float* __restrict__ w6, const float* __restrict__ b6,
    const float* __restrict__ w7, const float* __restrict__ b7,
    const float* __restrict__ w_out, const float* __restrict__ b_out,
    float* __restrict__ out, float* __restrict__ hfinal) {
  const int g = blockIdx.y;                       // group, uniform per block
  const int n = blockIdx.x * blockDim.x + threadIdx.x;  // point index
  const size_t pt = (size_t)g * NPTS + n;

  // ---- load input point (3 floats) ----
  const float x0 = x[pt * 3 + 0];
  const float x1 = x[pt * 3 + 1];
  const float x2 = x[pt * 3 + 2];

  float ha[64], hb[64];

  // ---- layer 0: 3 -> 64 ----
  {
    const float* wp = w0 + g * (64 * 3);
    const float* bp = b0 + g * 64;
    #pragma unroll
    for (int o = 0; o < 64; ++o) {
      float acc = bp[o];
      acc = fmaf(wp[o * 3 + 0], x0, acc);
      acc = fmaf(wp[o * 3 + 1], x1, acc);
      acc = fmaf(wp[o * 3 + 2], x2, acc);
      ha[o] = fmaxf(acc, 0.0f);
    }
  }

  // ---- layers 1..4: 64 -> 64 ----
  dense64_relu(w1 + g * 4096, b1 + g * 64, ha, hb);
  dense64_relu(w2 + g * 4096, b2 + g * 64, hb, ha);
  dense64_relu(w3 + g * 4096, b3 + g * 64, ha, hb);
  dense64_relu(w4 + g * 4096, b4 + g * 64, hb, ha);
  // after layer 4 (+concat semantics): input to layer 5 is [x0,x1,x2, ha[0..63]]

  // ---- layer 5: 67 -> 64 ----
  {
    const float* wp = w5 + g * (64 * 67);
    const float* bp = b5 + g * 64;
    #pragma unroll
    for (int o = 0; o < 64; ++o) {
      const float* wr = wp + o * 67;
      float acc = bp[o];
      acc = fmaf(wr[0], x0, acc);
      acc = fmaf(wr[1], x1, acc);
      acc = fmaf(wr[2], x2, acc);
      #pragma unroll
      for (int c = 0; c < 64; ++c) acc = fmaf(wr[3 + c], ha[c], acc);
      hb[o] = fmaxf(acc, 0.0f);
    }
  }

  // ---- layers 6..7: 64 -> 64 ----
  dense64_relu(w6 + g * 4096, b6 + g * 64, hb, ha);
  dense64_relu(w7 + g * 4096, b7 + g * 64, ha, hb);
  // final hidden h = hb

  // ---- write h (second output), 64 floats, float4-coalesced ----
  {
    float4* hp = (float4*)(hfinal + pt * 64);
    #pragma unroll
    for (int j = 0; j < 16; ++j) {
      hp[j] = make_float4(hb[4 * j + 0], hb[4 * j + 1], hb[4 * j + 2], hb[4 * j + 3]);
    }
  }

  // ---- output layer: 64 -> 4 (identity activation) ----
  {
    const float* wp = w_out + g * (OUT_CH * 64);
    const float* bp = b_out + g * OUT_CH;
    float o4[OUT_CH];
    #pragma unroll
    for (int o = 0; o < OUT_CH; ++o) {
      float acc = bp[o];
      #pragma unroll
      for (int c = 0; c < 64; ++c) acc = fmaf(wp[o * 64 + c], hb[c], acc);
      o4[o] = acc;
    }
    *(float4*)(out + pt * 4) = make_float4(o4[0], o4[1], o4[2], o4[3]);
  }
}

extern "C" void kernel_launch(void* const* d_in, const int* in_sizes, int n_in,
                              void* d_out, int out_size, void* d_ws, size_t ws_size,
                              hipStream_t stream) {
  const float* x  = (const float*)d_in[0];
  const float* w0 = (const float*)d_in[1];  const float* b0 = (const float*)d_in[2];
  const float* w1 = (const float*)d_in[3];  const float* b1 = (const float*)d_in[4];
  const float* w2 = (const float*)d_in[5];  const float* b2 = (const float*)d_in[6];
  const float* w3 = (const float*)d_in[7];  const float* b3 = (const float*)d_in[8];
  const float* w4 = (const float*)d_in[9];  const float* b4 = (const float*)d_in[10];
  const float* w5 = (const float*)d_in[11]; const float* b5 = (const float*)d_in[12];
  const float* w6 = (const float*)d_in[13]; const float* b6 = (const float*)d_in[14];
  const float* w7 = (const float*)d_in[15]; const float* b7 = (const float*)d_in[16];
  const float* w_out = (const float*)d_in[17];
  const float* b_out = (const float*)d_in[18];

  float* out    = (float*)d_out;                            // [G,N,4]
  float* hfinal = (float*)d_out + (size_t)NG * NPTS * OUT_CH;  // [G,N,64]

  dim3 grid(NPTS / 256, NG);
  dim3 block(256);
  mlp_fused_kernel<<<grid, block, 0, stream>>>(
      x, w0, b0, w1, b1, w2, b2, w3, b3, w4, b4, w5, b5, w6, b6, w7, b7,
      w_out, b_out, out, hfinal);
}

// Round 3
// 793.439 us; speedup vs baseline: 3.5556x; 3.5556x over previous
//
#include <hip/hip_runtime.h>

// MetaMultiParallelMLP on MFMA (gfx950): G=16, D=8, W=64, IN_CH=3, OUT_CH=4,
// skip-concat of x before layer 5. B=1, N=65536. fp32 in/out.
//
// Split-bf16 MFMA: v = vh + vl (bf16 RNE each); W*H ~= Wh*Hh + Wh*Hl + Wl*Hh.
// Per block: 4 waves x 32 points, activations in LDS (hi/lo bf16, XOR-swizzled),
// all LDS regions wave-private -> no __syncthreads anywhere.
// Weights pre-split into d_ws by prep kernel, padded [64][64] per layer slot.

#define NG 16
#define NPTS 65536

typedef __attribute__((ext_vector_type(8))) short bf16x8;
typedef __attribute__((ext_vector_type(4))) float f32x4;

#define SLOT_ELEMS 4096            // one [64][64] bf16 slot
#define GROUP_ELEMS (10 * SLOT_ELEMS)  // slots 0..7: layers (5 = cols 3..66), 8: L5 x-part, 9: w_out pad
#define WBUF_ELEMS (NG * GROUP_ELEMS)  // 655360 ushorts per buffer (hi, lo)

// ---------- bf16 split helpers (RNE, finite inputs) ----------
__device__ __forceinline__ unsigned short f2bf(float f) {
  unsigned u = __builtin_bit_cast(unsigned, f);
  u += 0x7FFFu + ((u >> 16) & 1u);
  return (unsigned short)(u >> 16);
}
__device__ __forceinline__ float bf2f(unsigned short h) {
  unsigned u = ((unsigned)h) << 16;
  return __builtin_bit_cast(float, u);
}

// ---------- prep: split fp32 weights into padded bf16 hi/lo slots ----------
__global__ __launch_bounds__(256) void prep_weights(
    const float* __restrict__ w0, const float* __restrict__ w1,
    const float* __restrict__ w2, const float* __restrict__ w3,
    const float* __restrict__ w4, const float* __restrict__ w5,
    const float* __restrict__ w6, const float* __restrict__ w7,
    const float* __restrict__ w_out,
    unsigned short* __restrict__ whi, unsigned short* __restrict__ wlo) {
  int idx = blockIdx.x * 256 + threadIdx.x;
  if (idx >= WBUF_ELEMS) return;
  int g = idx / GROUP_ELEMS;
  int rem = idx - g * GROUP_ELEMS;
  int slot = rem / SLOT_ELEMS;
  int rc = rem - slot * SLOT_ELEMS;
  int row = rc >> 6, col = rc & 63;
  float v = 0.0f;
  switch (slot) {
    case 0: if (col < 3) v = w0[g * 192 + row * 3 + col]; break;        // [64][3] pad
    case 1: v = w1[g * 4096 + row * 64 + col]; break;
    case 2: v = w2[g * 4096 + row * 64 + col]; break;
    case 3: v = w3[g * 4096 + row * 64 + col]; break;
    case 4: v = w4[g * 4096 + row * 64 + col]; break;
    case 5: v = w5[g * 4288 + row * 67 + 3 + col]; break;               // h-part cols 3..66
    case 6: v = w6[g * 4096 + row * 64 + col]; break;
    case 7: v = w7[g * 4096 + row * 64 + col]; break;
    case 8: if (col < 3) v = w5[g * 4288 + row * 67 + col]; break;      // x-part cols 0..2
    case 9: if (row < 4) v = w_out[g * 256 + row * 64 + col]; break;    // [4][64] pad rows
  }
  unsigned short h = f2bf(v);
  whi[idx] = h;
  wlo[idx] = f2bf(v - bf2f(h));
}

// ---------- main kernel pieces ----------
// MFMA fragment assumptions (16x16x32 bf16):
//   A: lane holds row=lane&15, k=(lane>>4)*8 + j (j=0..7, contiguous)
//   B: lane holds col=lane&15, k=(lane>>4)*8 + j
//   C/D: col=lane&15, row=(lane>>4)*4 + reg      [verified layout, learn_hip m89]
// LDS H layout: [pt][64 ci] bf16, 128 B rows, byte-in-row XOR ((pt&7)<<4) swizzle.

__device__ __forceinline__ void zeroC(f32x4 C[4][2]) {
#pragma unroll
  for (int mt = 0; mt < 4; ++mt)
#pragma unroll
    for (int nt = 0; nt < 2; ++nt) {
      f32x4 z = {0.f, 0.f, 0.f, 0.f};
      C[mt][nt] = z;
    }
}

__device__ __forceinline__ void dense_mfma(const unsigned short* __restrict__ Wh,
                                           const unsigned short* __restrict__ Wl,
                                           const char* Hh_b, const char* Hl_b,
                                           int pt0, int q, int c, f32x4 C[4][2]) {
  bf16x8 Bh[2][2], Bl[2][2];
#pragma unroll
  for (int nt = 0; nt < 2; ++nt) {
    int pt = pt0 + nt * 16 + c;
#pragma unroll
    for (int kt = 0; kt < 2; ++kt) {
      int off = pt * 128 + (((kt * 32 + q * 8) * 2) ^ ((pt & 7) << 4));
      Bh[nt][kt] = *(const bf16x8*)(Hh_b + off);
      Bl[nt][kt] = *(const bf16x8*)(Hl_b + off);
    }
  }
#pragma unroll
  for (int mt = 0; mt < 4; ++mt) {
#pragma unroll
    for (int kt = 0; kt < 2; ++kt) {
      bf16x8 Ah = *(const bf16x8*)(Wh + (mt * 16 + c) * 64 + kt * 32 + q * 8);
      bf16x8 Al = *(const bf16x8*)(Wl + (mt * 16 + c) * 64 + kt * 32 + q * 8);
#pragma unroll
      for (int nt = 0; nt < 2; ++nt) {
        C[mt][nt] = __builtin_amdgcn_mfma_f32_16x16x32_bf16(Ah, Bh[nt][kt], C[mt][nt], 0, 0, 0);
        C[mt][nt] = __builtin_amdgcn_mfma_f32_16x16x32_bf16(Ah, Bl[nt][kt], C[mt][nt], 0, 0, 0);
        C[mt][nt] = __builtin_amdgcn_mfma_f32_16x16x32_bf16(Al, Bh[nt][kt], C[mt][nt], 0, 0, 0);
      }
    }
  }
}

__device__ __forceinline__ void xpart_mfma(const unsigned short* __restrict__ Wh,
                                           const unsigned short* __restrict__ Wl,
                                           const unsigned short* Xh, const unsigned short* Xl,
                                           int pt0, int q, int c, f32x4 C[4][2]) {
  bf16x8 Bh[2], Bl[2];
#pragma unroll
  for (int nt = 0; nt < 2; ++nt) {
    bf16x8 bh = {0, 0, 0, 0, 0, 0, 0, 0}, bl = {0, 0, 0, 0, 0, 0, 0, 0};
    if (q == 0) {
      int pt = pt0 + nt * 16 + c;
      ushort4 vh = *(const ushort4*)(Xh + pt * 4);
      ushort4 vl = *(const ushort4*)(Xl + pt * 4);
      bh[0] = (short)vh.x; bh[1] = (short)vh.y; bh[2] = (short)vh.z; bh[3] = (short)vh.w;
      bl[0] = (short)vl.x; bl[1] = (short)vl.y; bl[2] = (short)vl.z; bl[3] = (short)vl.w;
    }
    Bh[nt] = bh; Bl[nt] = bl;
  }
#pragma unroll
  for (int mt = 0; mt < 4; ++mt) {
    bf16x8 Ah = *(const bf16x8*)(Wh + (mt * 16 + c) * 64 + q * 8);  // kt=0 only
    bf16x8 Al = *(const bf16x8*)(Wl + (mt * 16 + c) * 64 + q * 8);
#pragma unroll
    for (int nt = 0; nt < 2; ++nt) {
      C[mt][nt] = __builtin_amdgcn_mfma_f32_16x16x32_bf16(Ah, Bh[nt], C[mt][nt], 0, 0, 0);
      C[mt][nt] = __builtin_amdgcn_mfma_f32_16x16x32_bf16(Ah, Bl[nt], C[mt][nt], 0, 0, 0);
      C[mt][nt] = __builtin_amdgcn_mfma_f32_16x16x32_bf16(Al, Bh[nt], C[mt][nt], 0, 0, 0);
    }
  }
}

__device__ __forceinline__ void finish_layer(f32x4 C[4][2], const float* __restrict__ bias,
                                             char* Hh_b, char* Hl_b, int pt0, int q, int c) {
#pragma unroll
  for (int mt = 0; mt < 4; ++mt) {
    float4 bs = ((const float4*)bias)[mt * 4 + q];
#pragma unroll
    for (int nt = 0; nt < 2; ++nt) {
      f32x4 v = C[mt][nt];
      v[0] = fmaxf(v[0] + bs.x, 0.f);
      v[1] = fmaxf(v[1] + bs.y, 0.f);
      v[2] = fmaxf(v[2] + bs.z, 0.f);
      v[3] = fmaxf(v[3] + bs.w, 0.f);
      C[mt][nt] = v;
      unsigned short h0 = f2bf(v[0]), h1 = f2bf(v[1]), h2 = f2bf(v[2]), h3 = f2bf(v[3]);
      ushort4 uh = make_ushort4(h0, h1, h2, h3);
      ushort4 ul = make_ushort4(f2bf(v[0] - bf2f(h0)), f2bf(v[1] - bf2f(h1)),
                                f2bf(v[2] - bf2f(h2)), f2bf(v[3] - bf2f(h3)));
      int pt = pt0 + nt * 16 + c;
      int off = pt * 128 + ((mt * 32 + q * 8) ^ ((pt & 7) << 4));
      *(ushort4*)(Hh_b + off) = uh;
      *(ushort4*)(Hl_b + off) = ul;
    }
  }
}

__global__ __launch_bounds__(256) void mlp_mfma_kernel(
    const float* __restrict__ x,
    const float* __restrict__ b0, const float* __restrict__ b1,
    const float* __restrict__ b2, const float* __restrict__ b3,
    const float* __restrict__ b4, const float* __restrict__ b5,
    const float* __restrict__ b6, const float* __restrict__ b7,
    const float* __restrict__ b_out,
    const unsigned short* __restrict__ whi, const unsigned short* __restrict__ wlo,
    float* __restrict__ out, float* __restrict__ hfinal) {
  const int g = blockIdx.y;
  const int tid = threadIdx.x;
  const int wv = tid >> 6;
  const int lane = tid & 63;
  const int q = lane >> 4;
  const int c = lane & 15;
  const int n0 = blockIdx.x * 128;
  const int pt0 = wv * 32;  // wave's first block-local point

  __shared__ __attribute__((aligned(16))) unsigned short Hh[128 * 64];
  __shared__ __attribute__((aligned(16))) unsigned short Hl[128 * 64];
  __shared__ __attribute__((aligned(16))) unsigned short Xh[128 * 4];
  __shared__ __attribute__((aligned(16))) unsigned short Xl[128 * 4];
  char* Hh_b = (char*)Hh;
  char* Hl_b = (char*)Hl;

  const unsigned short* wg_hi = whi + g * GROUP_ELEMS;
  const unsigned short* wg_lo = wlo + g * GROUP_ELEMS;

  // ---- stage x (wave-local: lanes 0..31 stage this wave's 32 points) ----
  if (lane < 32) {
    int pt = pt0 + lane;
    const float* xp = x + ((size_t)g * NPTS + n0 + pt) * 3;
    float a0 = xp[0], a1 = xp[1], a2 = xp[2];
    unsigned short h0 = f2bf(a0), h1 = f2bf(a1), h2 = f2bf(a2);
    ushort4 vh = make_ushort4(h0, h1, h2, 0);
    ushort4 vl = make_ushort4(f2bf(a0 - bf2f(h0)), f2bf(a1 - bf2f(h1)), f2bf(a2 - bf2f(h2)), 0);
    *(ushort4*)(Xh + pt * 4) = vh;
    *(ushort4*)(Xl + pt * 4) = vl;
  }
  // No barrier: producers and consumers are the same wave; LDS ops are wave-ordered.

  f32x4 C[4][2];

  // layer 0: x -> 64
  zeroC(C);
  xpart_mfma(wg_hi + 0 * SLOT_ELEMS, wg_lo + 0 * SLOT_ELEMS, Xh, Xl, pt0, q, c, C);
  finish_layer(C, b0 + g * 64, Hh_b, Hl_b, pt0, q, c);

  // layers 1..4
  zeroC(C); dense_mfma(wg_hi + 1 * SLOT_ELEMS, wg_lo + 1 * SLOT_ELEMS, Hh_b, Hl_b, pt0, q, c, C);
  finish_layer(C, b1 + g * 64, Hh_b, Hl_b, pt0, q, c);
  zeroC(C); dense_mfma(wg_hi + 2 * SLOT_ELEMS, wg_lo + 2 * SLOT_ELEMS, Hh_b, Hl_b, pt0, q, c, C);
  finish_layer(C, b2 + g * 64, Hh_b, Hl_b, pt0, q, c);
  zeroC(C); dense_mfma(wg_hi + 3 * SLOT_ELEMS, wg_lo + 3 * SLOT_ELEMS, Hh_b, Hl_b, pt0, q, c, C);
  finish_layer(C, b3 + g * 64, Hh_b, Hl_b, pt0, q, c);
  zeroC(C); dense_mfma(wg_hi + 4 * SLOT_ELEMS, wg_lo + 4 * SLOT_ELEMS, Hh_b, Hl_b, pt0, q, c, C);
  finish_layer(C, b4 + g * 64, Hh_b, Hl_b, pt0, q, c);

  // layer 5: [x, h4] (ci=67) = x-part + h-part
  zeroC(C);
  xpart_mfma(wg_hi + 8 * SLOT_ELEMS, wg_lo + 8 * SLOT_ELEMS, Xh, Xl, pt0, q, c, C);
  dense_mfma(wg_hi + 5 * SLOT_ELEMS, wg_lo + 5 * SLOT_ELEMS, Hh_b, Hl_b, pt0, q, c, C);
  finish_layer(C, b5 + g * 64, Hh_b, Hl_b, pt0, q, c);

  // layers 6..7
  zeroC(C); dense_mfma(wg_hi + 6 * SLOT_ELEMS, wg_lo + 6 * SLOT_ELEMS, Hh_b, Hl_b, pt0, q, c, C);
  finish_layer(C, b6 + g * 64, Hh_b, Hl_b, pt0, q, c);
  zeroC(C); dense_mfma(wg_hi + 7 * SLOT_ELEMS, wg_lo + 7 * SLOT_ELEMS, Hh_b, Hl_b, pt0, q, c, C);
  finish_layer(C, b7 + g * 64, Hh_b, Hl_b, pt0, q, c);

  // write hfinal (fp32, exact from accumulators; full 64B lines per wave)
#pragma unroll
  for (int mt = 0; mt < 4; ++mt) {
#pragma unroll
    for (int nt = 0; nt < 2; ++nt) {
      size_t ptg = (size_t)g * NPTS + n0 + pt0 + nt * 16 + c;
      f32x4 v = C[mt][nt];
      *(float4*)(hfinal + ptg * 64 + mt * 16 + q * 4) = make_float4(v[0], v[1], v[2], v[3]);
    }
  }

  // out layer: 64 -> 4 (w_out padded to [16][64], rows 4..15 zero; mt=0 only)
  f32x4 Co[2];
  {
    f32x4 z = {0.f, 0.f, 0.f, 0.f};
    Co[0] = z; Co[1] = z;
  }
#pragma unroll
  for (int kt = 0; kt < 2; ++kt) {
    bf16x8 Ah = *(const bf16x8*)(wg_hi + 9 * SLOT_ELEMS + c * 64 + kt * 32 + q * 8);
    bf16x8 Al = *(const bf16x8*)(wg_lo + 9 * SLOT_ELEMS + c * 64 + kt * 32 + q * 8);
#pragma unroll
    for (int nt = 0; nt < 2; ++nt) {
      int pt = pt0 + nt * 16 + c;
      int off = pt * 128 + (((kt * 32 + q * 8) * 2) ^ ((pt & 7) << 4));
      bf16x8 Bh = *(const bf16x8*)(Hh_b + off);
      bf16x8 Bl = *(const bf16x8*)(Hl_b + off);
      Co[nt] = __builtin_amdgcn_mfma_f32_16x16x32_bf16(Ah, Bh, Co[nt], 0, 0, 0);
      Co[nt] = __builtin_amdgcn_mfma_f32_16x16x32_bf16(Ah, Bl, Co[nt], 0, 0, 0);
      Co[nt] = __builtin_amdgcn_mfma_f32_16x16x32_bf16(Al, Bh, Co[nt], 0, 0, 0);
    }
  }
  if (q == 0) {  // rows 0..3 = oc 0..3 live in q==0 lanes
    float4 bo = *(const float4*)(b_out + g * 4);
#pragma unroll
    for (int nt = 0; nt < 2; ++nt) {
      size_t ptg = (size_t)g * NPTS + n0 + pt0 + nt * 16 + c;
      *(float4*)(out + ptg * 4) =
          make_float4(Co[nt][0] + bo.x, Co[nt][1] + bo.y, Co[nt][2] + bo.z, Co[nt][3] + bo.w);
    }
  }
}

extern "C" void kernel_launch(void* const* d_in, const int* in_sizes, int n_in,
                              void* d_out, int out_size, void* d_ws, size_t ws_size,
                              hipStream_t stream) {
  const float* x  = (const float*)d_in[0];
  const float* w0 = (const float*)d_in[1];  const float* b0 = (const float*)d_in[2];
  const float* w1 = (const float*)d_in[3];  const float* b1 = (const float*)d_in[4];
  const float* w2 = (const float*)d_in[5];  const float* b2 = (const float*)d_in[6];
  const float* w3 = (const float*)d_in[7];  const float* b3 = (const float*)d_in[8];
  const float* w4 = (const float*)d_in[9];  const float* b4 = (const float*)d_in[10];
  const float* w5 = (const float*)d_in[11]; const float* b5 = (const float*)d_in[12];
  const float* w6 = (const float*)d_in[13]; const float* b6 = (const float*)d_in[14];
  const float* w7 = (const float*)d_in[15]; const float* b7 = (const float*)d_in[16];
  const float* w_out = (const float*)d_in[17];
  const float* b_out = (const float*)d_in[18];

  float* out    = (float*)d_out;                               // [G,N,4]
  float* hfinal = (float*)d_out + (size_t)NG * NPTS * 4;       // [G,N,64]

  // d_ws: whi[WBUF_ELEMS] ++ wlo[WBUF_ELEMS] ushorts = 2.62 MB total
  unsigned short* whi = (unsigned short*)d_ws;
  unsigned short* wlo = whi + WBUF_ELEMS;

  prep_weights<<<dim3((WBUF_ELEMS + 255) / 256), dim3(256), 0, stream>>>(
      w0, w1, w2, w3, w4, w5, w6, w7, w_out, whi, wlo);

  mlp_mfma_kernel<<<dim3(NPTS / 128, NG), dim3(256), 0, stream>>>(
      x, b0, b1, b2, b3, b4, b5, b6, b7, b_out, whi, wlo, out, hfinal);
}

// Round 7
// 781.808 us; speedup vs baseline: 3.6085x; 1.0149x over previous
//
#include <hip/hip_runtime.h>
#include <hip/hip_bf16.h>

// MetaMultiParallelMLP on MFMA (gfx950): G=16, D=8, W=64, IN_CH=3, OUT_CH=4,
// skip-concat of x before layer 5. B=1, N=65536. fp32 in/out.
//
// Split-bf16 MFMA: v = vh + vl; W*H ~= Wh*Hh + Wh*Hl + Wl*Hh.
// KEY TRICK: weight COLUMNS are pre-permuted by sigma so that the C/D
// accumulator fragment of layer k, after bias+relu+bf16-split, IS the B
// fragment of layer k+1 in the same lane. Activations never leave registers:
// no LDS, no cross-lane ops, no barriers.
//   C/D: lane(q,c) holds rows {mt*16+q*4+r}, col c   [m89 layout]
//   B:   lane(q,c) holds k = kt*32+q*8+j,   col c
//   pack: B(kt)[j] := C[2*kt + (j>>2)][j&3]  =>  sigma(k) = (kt*2+(j>>2))*16+q*4+(j&3)

#define NG 16
#define NPTS 65536

typedef __attribute__((ext_vector_type(8))) short bf16x8;
typedef __attribute__((ext_vector_type(4))) float f32x4;
typedef __attribute__((ext_vector_type(4))) int i32x4;

#define SLOT_ELEMS 4096                 // one [64][64] bf16 slot
#define GROUP_ELEMS (10 * SLOT_ELEMS)   // 0: L0 x-part, 1..7: dense (5=h-part), 8: L5 x-part, 9: w_out
#define WBUF_ELEMS (NG * GROUP_ELEMS)

// ---------- bf16 helpers ----------
__device__ __forceinline__ unsigned short f2bf(float f) {
  unsigned u = __builtin_bit_cast(unsigned, f);
  u += 0x7FFFu + ((u >> 16) & 1u);
  return (unsigned short)(u >> 16);
}
__device__ __forceinline__ float bf2f(unsigned short h) {
  return __builtin_bit_cast(float, ((unsigned)h) << 16);
}
__device__ __forceinline__ unsigned pkbf(float a, float b) {
  __hip_bfloat162 t = __float22bfloat162_rn(make_float2(a, b));  // a -> low 16, b -> high 16
  unsigned u;
  __builtin_memcpy(&u, &t, 4);
  return u;
}
__device__ __forceinline__ float lo2f(unsigned u) { return __builtin_bit_cast(float, u << 16); }
__device__ __forceinline__ float hi2f(unsigned u) { return __builtin_bit_cast(float, u & 0xFFFF0000u); }
__device__ __forceinline__ bf16x8 pack4(unsigned a, unsigned b, unsigned cc, unsigned d) {
  i32x4 t;
  t[0] = (int)a; t[1] = (int)b; t[2] = (int)cc; t[3] = (int)d;
  return __builtin_bit_cast(bf16x8, t);
}

// sigma: MFMA k-position -> weight source column
__device__ __forceinline__ int sig(int k) {
  int kt = k >> 5, qq = (k >> 3) & 3, j = k & 7;
  return (kt * 2 + (j >> 2)) * 16 + qq * 4 + (j & 3);
}

// ---------- prep: split fp32 weights into bf16 hi/lo, column-permuted ----------
__global__ __launch_bounds__(256) void prep_weights(
    const float* __restrict__ w0, const float* __restrict__ w1,
    const float* __restrict__ w2, const float* __restrict__ w3,
    const float* __restrict__ w4, const float* __restrict__ w5,
    const float* __restrict__ w6, const float* __restrict__ w7,
    const float* __restrict__ w_out,
    unsigned short* __restrict__ whi, unsigned short* __restrict__ wlo) {
  int idx = blockIdx.x * 256 + threadIdx.x;
  if (idx >= WBUF_ELEMS) return;
  int g = idx / GROUP_ELEMS;
  int rem = idx - g * GROUP_ELEMS;
  int slot = rem / SLOT_ELEMS;
  int rc = rem - slot * SLOT_ELEMS;
  int row = rc >> 6, col = rc & 63;
  int sc = sig(col);
  float v = 0.0f;
  switch (slot) {
    case 0: if (col < 3) v = w0[g * 192 + row * 3 + col]; break;          // x-part: no sigma
    case 1: v = w1[g * 4096 + row * 64 + sc]; break;
    case 2: v = w2[g * 4096 + row * 64 + sc]; break;
    case 3: v = w3[g * 4096 + row * 64 + sc]; break;
    case 4: v = w4[g * 4096 + row * 64 + sc]; break;
    case 5: v = w5[g * 4288 + row * 67 + 3 + sc]; break;                  // h-part cols
    case 6: v = w6[g * 4096 + row * 64 + sc]; break;
    case 7: v = w7[g * 4096 + row * 64 + sc]; break;
    case 8: if (col < 3) v = w5[g * 4288 + row * 67 + col]; break;        // x-part: no sigma
    case 9: if (row < 4) v = w_out[g * 256 + row * 64 + sc]; break;
  }
  unsigned short h = f2bf(v);
  whi[idx] = h;
  wlo[idx] = f2bf(v - bf2f(h));
}

// ---------- device pieces ----------
__device__ __forceinline__ void zeroC(f32x4 (&C)[4][2]) {
#pragma unroll
  for (int mt = 0; mt < 4; ++mt)
#pragma unroll
    for (int nt = 0; nt < 2; ++nt) {
      f32x4 z = {0.f, 0.f, 0.f, 0.f};
      C[mt][nt] = z;
    }
}

// bias+relu, write back to C (for hfinal), and pack B fragments for next layer.
__device__ __forceinline__ void cvt_to_B(f32x4 (&C)[4][2], int nt, const float4* __restrict__ bias4,
                                         int q, bf16x8 (&Bh)[2][2], bf16x8 (&Bl)[2][2]) {
  float v[4][4];
#pragma unroll
  for (int mt = 0; mt < 4; ++mt) {
    float4 bs = bias4[mt * 4 + q];
    f32x4 cc = C[mt][nt];
    float t0 = fmaxf(cc[0] + bs.x, 0.f);
    float t1 = fmaxf(cc[1] + bs.y, 0.f);
    float t2 = fmaxf(cc[2] + bs.z, 0.f);
    float t3 = fmaxf(cc[3] + bs.w, 0.f);
    v[mt][0] = t0; v[mt][1] = t1; v[mt][2] = t2; v[mt][3] = t3;
    cc[0] = t0; cc[1] = t1; cc[2] = t2; cc[3] = t3;
    C[mt][nt] = cc;
  }
#pragma unroll
  for (int kt = 0; kt < 2; ++kt) {
    const float* a = v[2 * kt];
    const float* b = v[2 * kt + 1];
    unsigned u0 = pkbf(a[0], a[1]), u1 = pkbf(a[2], a[3]);
    unsigned u2 = pkbf(b[0], b[1]), u3 = pkbf(b[2], b[3]);
    Bh[nt][kt] = pack4(u0, u1, u2, u3);
    unsigned l0 = pkbf(a[0] - lo2f(u0), a[1] - hi2f(u0));
    unsigned l1 = pkbf(a[2] - lo2f(u1), a[3] - hi2f(u1));
    unsigned l2 = pkbf(b[0] - lo2f(u2), b[1] - hi2f(u2));
    unsigned l3 = pkbf(b[2] - lo2f(u3), b[3] - hi2f(u3));
    Bl[nt][kt] = pack4(l0, l1, l2, l3);
  }
}

__device__ __forceinline__ void dense(const unsigned short* __restrict__ wh,
                                      const unsigned short* __restrict__ wl,
                                      int q, int c, const bf16x8 (&Bh)[2][2], const bf16x8 (&Bl)[2][2],
                                      f32x4 (&C)[4][2]) {
#pragma unroll
  for (int mt = 0; mt < 4; ++mt) {
#pragma unroll
    for (int kt = 0; kt < 2; ++kt) {
      bf16x8 Ah = *(const bf16x8*)(wh + (mt * 16 + c) * 64 + kt * 32 + q * 8);
      bf16x8 Al = *(const bf16x8*)(wl + (mt * 16 + c) * 64 + kt * 32 + q * 8);
#pragma unroll
      for (int nt = 0; nt < 2; ++nt) {
        C[mt][nt] = __builtin_amdgcn_mfma_f32_16x16x32_bf16(Ah, Bh[nt][kt], C[mt][nt], 0, 0, 0);
        C[mt][nt] = __builtin_amdgcn_mfma_f32_16x16x32_bf16(Ah, Bl[nt][kt], C[mt][nt], 0, 0, 0);
        C[mt][nt] = __builtin_amdgcn_mfma_f32_16x16x32_bf16(Al, Bh[nt][kt], C[mt][nt], 0, 0, 0);
      }
    }
  }
}

// x contribution (k=0..2 live in kt=0, q'=0 lanes, j order = feature order)
__device__ __forceinline__ void xpart(const unsigned short* __restrict__ wh,
                                      const unsigned short* __restrict__ wl,
                                      int q, int c, const float (&xr)[2][3], f32x4 (&C)[4][2]) {
  bf16x8 Bxh[2], Bxl[2];
#pragma unroll
  for (int nt = 0; nt < 2; ++nt) {
    unsigned u0 = 0, u1 = 0, l0 = 0, l1 = 0;
    if (q == 0) {
      u0 = pkbf(xr[nt][0], xr[nt][1]);
      u1 = pkbf(xr[nt][2], 0.f);
      l0 = pkbf(xr[nt][0] - lo2f(u0), xr[nt][1] - hi2f(u0));
      l1 = pkbf(xr[nt][2] - lo2f(u1), 0.f);
    }
    Bxh[nt] = pack4(u0, u1, 0, 0);
    Bxl[nt] = pack4(l0, l1, 0, 0);
  }
#pragma unroll
  for (int mt = 0; mt < 4; ++mt) {
    bf16x8 Ah = *(const bf16x8*)(wh + (mt * 16 + c) * 64 + q * 8);  // kt=0 only
    bf16x8 Al = *(const bf16x8*)(wl + (mt * 16 + c) * 64 + q * 8);
#pragma unroll
    for (int nt = 0; nt < 2; ++nt) {
      C[mt][nt] = __builtin_amdgcn_mfma_f32_16x16x32_bf16(Ah, Bxh[nt], C[mt][nt], 0, 0, 0);
      C[mt][nt] = __builtin_amdgcn_mfma_f32_16x16x32_bf16(Ah, Bxl[nt], C[mt][nt], 0, 0, 0);
      C[mt][nt] = __builtin_amdgcn_mfma_f32_16x16x32_bf16(Al, Bxh[nt], C[mt][nt], 0, 0, 0);
    }
  }
}

__global__ __launch_bounds__(256, 4) void mlp_mfma_kernel(
    const float* __restrict__ x,
    const float* __restrict__ b0, const float* __restrict__ b1,
    const float* __restrict__ b2, const float* __restrict__ b3,
    const float* __restrict__ b4, const float* __restrict__ b5,
    const float* __restrict__ b6, const float* __restrict__ b7,
    const float* __restrict__ b_out,
    const unsigned short* __restrict__ whi, const unsigned short* __restrict__ wlo,
    float* __restrict__ out, float* __restrict__ hfinal) {
  const int g = blockIdx.y;
  const int lane = threadIdx.x & 63;
  const int wv = threadIdx.x >> 6;
  const int q = lane >> 4;
  const int c = lane & 15;
  const int n0 = blockIdx.x * 128 + wv * 32;  // wave's first point within group

  const unsigned short* wgh = whi + (size_t)g * GROUP_ELEMS;
  const unsigned short* wgl = wlo + (size_t)g * GROUP_ELEMS;

  // raw x for this lane's two nt-points (rebuilt into B frags at L0 and L5)
  float xr[2][3];
#pragma unroll
  for (int nt = 0; nt < 2; ++nt) {
    const float* xp = x + ((size_t)g * NPTS + n0 + nt * 16 + c) * 3;
    xr[nt][0] = xp[0]; xr[nt][1] = xp[1]; xr[nt][2] = xp[2];
  }

  f32x4 C[4][2];
  bf16x8 Bh[2][2], Bl[2][2];

  // layer 0: x -> 64
  zeroC(C);
  xpart(wgh + 0 * SLOT_ELEMS, wgl + 0 * SLOT_ELEMS, q, c, xr, C);
  cvt_to_B(C, 0, (const float4*)(b0 + g * 64), q, Bh, Bl);
  cvt_to_B(C, 1, (const float4*)(b0 + g * 64), q, Bh, Bl);

  // layers 1..4
  zeroC(C); dense(wgh + 1 * SLOT_ELEMS, wgl + 1 * SLOT_ELEMS, q, c, Bh, Bl, C);
  cvt_to_B(C, 0, (const float4*)(b1 + g * 64), q, Bh, Bl);
  cvt_to_B(C, 1, (const float4*)(b1 + g * 64), q, Bh, Bl);
  zeroC(C); dense(wgh + 2 * SLOT_ELEMS, wgl + 2 * SLOT_ELEMS, q, c, Bh, Bl, C);
  cvt_to_B(C, 0, (const float4*)(b2 + g * 64), q, Bh, Bl);
  cvt_to_B(C, 1, (const float4*)(b2 + g * 64), q, Bh, Bl);
  zeroC(C); dense(wgh + 3 * SLOT_ELEMS, wgl + 3 * SLOT_ELEMS, q, c, Bh, Bl, C);
  cvt_to_B(C, 0, (const float4*)(b3 + g * 64), q, Bh, Bl);
  cvt_to_B(C, 1, (const float4*)(b3 + g * 64), q, Bh, Bl);
  zeroC(C); dense(wgh + 4 * SLOT_ELEMS, wgl + 4 * SLOT_ELEMS, q, c, Bh, Bl, C);
  cvt_to_B(C, 0, (const float4*)(b4 + g * 64), q, Bh, Bl);
  cvt_to_B(C, 1, (const float4*)(b4 + g * 64), q, Bh, Bl);

  // layer 5: concat([x, h4]) -> x-part (slot 8) + dense h-part (slot 5)
  zeroC(C);
  xpart(wgh + 8 * SLOT_ELEMS, wgl + 8 * SLOT_ELEMS, q, c, xr, C);
  dense(wgh + 5 * SLOT_ELEMS, wgl + 5 * SLOT_ELEMS, q, c, Bh, Bl, C);
  cvt_to_B(C, 0, (const float4*)(b5 + g * 64), q, Bh, Bl);
  cvt_to_B(C, 1, (const float4*)(b5 + g * 64), q, Bh, Bl);

  // layers 6..7
  zeroC(C); dense(wgh + 6 * SLOT_ELEMS, wgl + 6 * SLOT_ELEMS, q, c, Bh, Bl, C);
  cvt_to_B(C, 0, (const float4*)(b6 + g * 64), q, Bh, Bl);
  cvt_to_B(C, 1, (const float4*)(b6 + g * 64), q, Bh, Bl);
  zeroC(C); dense(wgh + 7 * SLOT_ELEMS, wgl + 7 * SLOT_ELEMS, q, c, Bh, Bl, C);
  cvt_to_B(C, 0, (const float4*)(b7 + g * 64), q, Bh, Bl);  // also leaves relu'd h in C
  cvt_to_B(C, 1, (const float4*)(b7 + g * 64), q, Bh, Bl);

  // write hfinal (fp32, post-relu, from C; feature = mt*16+q*4+r)
#pragma unroll
  for (int mt = 0; mt < 4; ++mt) {
#pragma unroll
    for (int nt = 0; nt < 2; ++nt) {
      size_t ptg = (size_t)g * NPTS + n0 + nt * 16 + c;
      f32x4 v = C[mt][nt];
      *(float4*)(hfinal + ptg * 64 + mt * 16 + q * 4) = make_float4(v[0], v[1], v[2], v[3]);
    }
  }

  // out layer: 64 -> 4 (slot 9 rows 4..15 zero; result rows 0..3 live in q==0)
  f32x4 Co[2];
  {
    f32x4 z = {0.f, 0.f, 0.f, 0.f};
    Co[0] = z; Co[1] = z;
  }
#pragma unroll
  for (int kt = 0; kt < 2; ++kt) {
    bf16x8 Ah = *(const bf16x8*)(wgh + 9 * SLOT_ELEMS + c * 64 + kt * 32 + q * 8);
    bf16x8 Al = *(const bf16x8*)(wgl + 9 * SLOT_ELEMS + c * 64 + kt * 32 + q * 8);
#pragma unroll
    for (int nt = 0; nt < 2; ++nt) {
      Co[nt] = __builtin_amdgcn_mfma_f32_16x16x32_bf16(Ah, Bh[nt][kt], Co[nt], 0, 0, 0);
      Co[nt] = __builtin_amdgcn_mfma_f32_16x16x32_bf16(Ah, Bl[nt][kt], Co[nt], 0, 0, 0);
      Co[nt] = __builtin_amdgcn_mfma_f32_16x16x32_bf16(Al, Bh[nt][kt], Co[nt], 0, 0, 0);
    }
  }
  if (q == 0) {
    float4 bo = *(const float4*)(b_out + g * 4);
#pragma unroll
    for (int nt = 0; nt < 2; ++nt) {
      size_t ptg = (size_t)g * NPTS + n0 + nt * 16 + c;
      *(float4*)(out + ptg * 4) =
          make_float4(Co[nt][0] + bo.x, Co[nt][1] + bo.y, Co[nt][2] + bo.z, Co[nt][3] + bo.w);
    }
  }
}

extern "C" void kernel_launch(void* const* d_in, const int* in_sizes, int n_in,
                              void* d_out, int out_size, void* d_ws, size_t ws_size,
                              hipStream_t stream) {
  const float* x  = (const float*)d_in[0];
  const float* w0 = (const float*)d_in[1];  const float* b0 = (const float*)d_in[2];
  const float* w1 = (const float*)d_in[3];  const float* b1 = (const float*)d_in[4];
  const float* w2 = (const float*)d_in[5];  const float* b2 = (const float*)d_in[6];
  const float* w3 = (const float*)d_in[7];  const float* b3 = (const float*)d_in[8];
  const float* w4 = (const float*)d_in[9];  const float* b4 = (const float*)d_in[10];
  const float* w5 = (const float*)d_in[11]; const float* b5 = (const float*)d_in[12];
  const float* w6 = (const float*)d_in[13]; const float* b6 = (const float*)d_in[14];
  const float* w7 = (const float*)d_in[15]; const float* b7 = (const float*)d_in[16];
  const float* w_out = (const float*)d_in[17];
  const float* b_out = (const float*)d_in[18];

  float* out    = (float*)d_out;                          // [G,N,4]
  float* hfinal = (float*)d_out + (size_t)NG * NPTS * 4;  // [G,N,64]

  unsigned short* whi = (unsigned short*)d_ws;
  unsigned short* wlo = whi + WBUF_ELEMS;

  prep_weights<<<dim3((WBUF_ELEMS + 255) / 256), dim3(256), 0, stream>>>(
      w0, w1, w2, w3, w4, w5, w6, w7, w_out, whi, wlo);

  mlp_mfma_kernel<<<dim3(NPTS / 128, NG), dim3(256), 0, stream>>>(
      x, b0, b1, b2, b3, b4, b5, b6, b7, b_out, whi, wlo, out, hfinal);
}

// Round 8
// 582.540 us; speedup vs baseline: 4.8429x; 1.3421x over previous
//
#include <hip/hip_runtime.h>
#include <hip/hip_bf16.h>

// MetaMultiParallelMLP on MFMA (gfx950): G=16, D=8, W=64, IN_CH=3, OUT_CH=4,
// skip-concat of x before layer 5. B=1, N=65536. fp32 in/out.
//
// Split-bf16 MFMA: v = vh + vl; W*H ~= Wh*Hh + Wh*Hl + Wl*Hh.
// Register-chained activations (sigma-permuted weight columns make layer k's
// C fragment == layer k+1's B fragment, no LDS / no barriers), now with
// NT=4 (64 points/wave) and batched A-fragment loads for ILP:
//   per layer: load 8x Ah (one vmcnt batch) -> 64 MFMAs -> stream 8x Al
//   under the last 32 MFMAs. Each A-load feeds 12 MFMAs.

#define NG 16
#define NPTS 65536
#define NT 4                            // nt-tiles (16 points each) per wave

typedef __attribute__((ext_vector_type(8))) short bf16x8;
typedef __attribute__((ext_vector_type(4))) float f32x4;
typedef __attribute__((ext_vector_type(4))) int i32x4;

#define SLOT_ELEMS 4096                 // one [64][64] bf16 slot
#define GROUP_ELEMS (10 * SLOT_ELEMS)   // 0: L0 x-part, 1..7: dense (5=h-part), 8: L5 x-part, 9: w_out
#define WBUF_ELEMS (NG * GROUP_ELEMS)

// ---------- bf16 helpers ----------
__device__ __forceinline__ unsigned short f2bf(float f) {
  unsigned u = __builtin_bit_cast(unsigned, f);
  u += 0x7FFFu + ((u >> 16) & 1u);
  return (unsigned short)(u >> 16);
}
__device__ __forceinline__ float bf2f(unsigned short h) {
  return __builtin_bit_cast(float, ((unsigned)h) << 16);
}
__device__ __forceinline__ unsigned pkbf(float a, float b) {
  __hip_bfloat162 t = __float22bfloat162_rn(make_float2(a, b));  // a -> low 16, b -> high 16
  unsigned u;
  __builtin_memcpy(&u, &t, 4);
  return u;
}
__device__ __forceinline__ float lo2f(unsigned u) { return __builtin_bit_cast(float, u << 16); }
__device__ __forceinline__ float hi2f(unsigned u) { return __builtin_bit_cast(float, u & 0xFFFF0000u); }
__device__ __forceinline__ bf16x8 pack4(unsigned a, unsigned b, unsigned cc, unsigned d) {
  i32x4 t;
  t[0] = (int)a; t[1] = (int)b; t[2] = (int)cc; t[3] = (int)d;
  return __builtin_bit_cast(bf16x8, t);
}

// sigma: MFMA k-position -> weight source column
__device__ __forceinline__ int sig(int k) {
  int kt = k >> 5, qq = (k >> 3) & 3, j = k & 7;
  return (kt * 2 + (j >> 2)) * 16 + qq * 4 + (j & 3);
}

// ---------- prep: split fp32 weights into bf16 hi/lo, column-permuted ----------
__global__ __launch_bounds__(256) void prep_weights(
    const float* __restrict__ w0, const float* __restrict__ w1,
    const float* __restrict__ w2, const float* __restrict__ w3,
    const float* __restrict__ w4, const float* __restrict__ w5,
    const float* __restrict__ w6, const float* __restrict__ w7,
    const float* __restrict__ w_out,
    unsigned short* __restrict__ whi, unsigned short* __restrict__ wlo) {
  int idx = blockIdx.x * 256 + threadIdx.x;
  if (idx >= WBUF_ELEMS) return;
  int g = idx / GROUP_ELEMS;
  int rem = idx - g * GROUP_ELEMS;
  int slot = rem / SLOT_ELEMS;
  int rc = rem - slot * SLOT_ELEMS;
  int row = rc >> 6, col = rc & 63;
  int sc = sig(col);
  float v = 0.0f;
  switch (slot) {
    case 0: if (col < 3) v = w0[g * 192 + row * 3 + col]; break;          // x-part: no sigma
    case 1: v = w1[g * 4096 + row * 64 + sc]; break;
    case 2: v = w2[g * 4096 + row * 64 + sc]; break;
    case 3: v = w3[g * 4096 + row * 64 + sc]; break;
    case 4: v = w4[g * 4096 + row * 64 + sc]; break;
    case 5: v = w5[g * 4288 + row * 67 + 3 + sc]; break;                  // h-part cols
    case 6: v = w6[g * 4096 + row * 64 + sc]; break;
    case 7: v = w7[g * 4096 + row * 64 + sc]; break;
    case 8: if (col < 3) v = w5[g * 4288 + row * 67 + col]; break;        // x-part: no sigma
    case 9: if (row < 4) v = w_out[g * 256 + row * 64 + sc]; break;
  }
  unsigned short h = f2bf(v);
  whi[idx] = h;
  wlo[idx] = f2bf(v - bf2f(h));
}

// ---------- device pieces ----------
__device__ __forceinline__ void zeroC(f32x4 (&C)[4][NT]) {
#pragma unroll
  for (int mt = 0; mt < 4; ++mt)
#pragma unroll
    for (int nt = 0; nt < NT; ++nt) {
      f32x4 z = {0.f, 0.f, 0.f, 0.f};
      C[mt][nt] = z;
    }
}

// bias+relu for all nt, write back to C (kept for hfinal), pack next-layer B frags.
__device__ __forceinline__ void cvt_all(f32x4 (&C)[4][NT], const float4* __restrict__ bias4,
                                        int q, bf16x8 (&Bh)[NT][2], bf16x8 (&Bl)[NT][2]) {
  float4 bs[4];
#pragma unroll
  for (int mt = 0; mt < 4; ++mt) bs[mt] = bias4[mt * 4 + q];
#pragma unroll
  for (int nt = 0; nt < NT; ++nt) {
    float v[4][4];
#pragma unroll
    for (int mt = 0; mt < 4; ++mt) {
      f32x4 cc = C[mt][nt];
      float t0 = fmaxf(cc[0] + bs[mt].x, 0.f);
      float t1 = fmaxf(cc[1] + bs[mt].y, 0.f);
      float t2 = fmaxf(cc[2] + bs[mt].z, 0.f);
      float t3 = fmaxf(cc[3] + bs[mt].w, 0.f);
      v[mt][0] = t0; v[mt][1] = t1; v[mt][2] = t2; v[mt][3] = t3;
      cc[0] = t0; cc[1] = t1; cc[2] = t2; cc[3] = t3;
      C[mt][nt] = cc;
    }
#pragma unroll
    for (int kt = 0; kt < 2; ++kt) {
      const float* a = v[2 * kt];
      const float* b = v[2 * kt + 1];
      unsigned u0 = pkbf(a[0], a[1]), u1 = pkbf(a[2], a[3]);
      unsigned u2 = pkbf(b[0], b[1]), u3 = pkbf(b[2], b[3]);
      Bh[nt][kt] = pack4(u0, u1, u2, u3);
      unsigned l0 = pkbf(a[0] - lo2f(u0), a[1] - hi2f(u0));
      unsigned l1 = pkbf(a[2] - lo2f(u1), a[3] - hi2f(u1));
      unsigned l2 = pkbf(b[0] - lo2f(u2), b[1] - hi2f(u2));
      unsigned l3 = pkbf(b[2] - lo2f(u3), b[3] - hi2f(u3));
      Bl[nt][kt] = pack4(l0, l1, l2, l3);
    }
  }
}

// dense 64->64: batch-load Ah (8x16B, one wait), 64 MFMAs, then stream Al
// loads under the remaining 32 MFMAs.
__device__ __forceinline__ void dense(const unsigned short* __restrict__ wh,
                                      const unsigned short* __restrict__ wl,
                                      int q, int c,
                                      const bf16x8 (&Bh)[NT][2], const bf16x8 (&Bl)[NT][2],
                                      f32x4 (&C)[4][NT]) {
  bf16x8 Ah[4][2];
#pragma unroll
  for (int mt = 0; mt < 4; ++mt)
#pragma unroll
    for (int kt = 0; kt < 2; ++kt)
      Ah[mt][kt] = *(const bf16x8*)(wh + (mt * 16 + c) * 64 + kt * 32 + q * 8);

#pragma unroll
  for (int mt = 0; mt < 4; ++mt)
#pragma unroll
    for (int kt = 0; kt < 2; ++kt) {
#pragma unroll
      for (int nt = 0; nt < NT; ++nt)
        C[mt][nt] = __builtin_amdgcn_mfma_f32_16x16x32_bf16(Ah[mt][kt], Bh[nt][kt], C[mt][nt], 0, 0, 0);
#pragma unroll
      for (int nt = 0; nt < NT; ++nt)
        C[mt][nt] = __builtin_amdgcn_mfma_f32_16x16x32_bf16(Ah[mt][kt], Bl[nt][kt], C[mt][nt], 0, 0, 0);
    }

#pragma unroll
  for (int mt = 0; mt < 4; ++mt)
#pragma unroll
    for (int kt = 0; kt < 2; ++kt) {
      bf16x8 Al = *(const bf16x8*)(wl + (mt * 16 + c) * 64 + kt * 32 + q * 8);
#pragma unroll
      for (int nt = 0; nt < NT; ++nt)
        C[mt][nt] = __builtin_amdgcn_mfma_f32_16x16x32_bf16(Al, Bh[nt][kt], C[mt][nt], 0, 0, 0);
    }
}

// x contribution (k=0..2 live in kt=0, q'==0 lanes, j order = feature order)
__device__ __forceinline__ void xpart(const unsigned short* __restrict__ wh,
                                      const unsigned short* __restrict__ wl,
                                      int q, int c, const float (&xr)[NT][3], f32x4 (&C)[4][NT]) {
  bf16x8 Bxh[NT], Bxl[NT];
#pragma unroll
  for (int nt = 0; nt < NT; ++nt) {
    unsigned u0 = 0, u1 = 0, l0 = 0, l1 = 0;
    if (q == 0) {
      u0 = pkbf(xr[nt][0], xr[nt][1]);
      u1 = pkbf(xr[nt][2], 0.f);
      l0 = pkbf(xr[nt][0] - lo2f(u0), xr[nt][1] - hi2f(u0));
      l1 = pkbf(xr[nt][2] - lo2f(u1), 0.f);
    }
    Bxh[nt] = pack4(u0, u1, 0, 0);
    Bxl[nt] = pack4(l0, l1, 0, 0);
  }
#pragma unroll
  for (int mt = 0; mt < 4; ++mt) {
    bf16x8 Ah = *(const bf16x8*)(wh + (mt * 16 + c) * 64 + q * 8);  // kt=0 only
    bf16x8 Al = *(const bf16x8*)(wl + (mt * 16 + c) * 64 + q * 8);
#pragma unroll
    for (int nt = 0; nt < NT; ++nt) {
      C[mt][nt] = __builtin_amdgcn_mfma_f32_16x16x32_bf16(Ah, Bxh[nt], C[mt][nt], 0, 0, 0);
      C[mt][nt] = __builtin_amdgcn_mfma_f32_16x16x32_bf16(Ah, Bxl[nt], C[mt][nt], 0, 0, 0);
      C[mt][nt] = __builtin_amdgcn_mfma_f32_16x16x32_bf16(Al, Bxh[nt], C[mt][nt], 0, 0, 0);
    }
  }
}

__global__ __launch_bounds__(256, 2) void mlp_mfma_kernel(
    const float* __restrict__ x,
    const float* __restrict__ b0, const float* __restrict__ b1,
    const float* __restrict__ b2, const float* __restrict__ b3,
    const float* __restrict__ b4, const float* __restrict__ b5,
    const float* __restrict__ b6, const float* __restrict__ b7,
    const float* __restrict__ b_out,
    const unsigned short* __restrict__ whi, const unsigned short* __restrict__ wlo,
    float* __restrict__ out, float* __restrict__ hfinal) {
  const int g = blockIdx.y;
  const int lane = threadIdx.x & 63;
  const int wv = threadIdx.x >> 6;
  const int q = lane >> 4;
  const int c = lane & 15;
  const int n0 = blockIdx.x * (64 * 4) + wv * 64;  // wave's first point within group

  const unsigned short* wgh = whi + (size_t)g * GROUP_ELEMS;
  const unsigned short* wgl = wlo + (size_t)g * GROUP_ELEMS;

  // raw x for this lane's NT points (rebuilt into B frags at L0 and L5)
  float xr[NT][3];
#pragma unroll
  for (int nt = 0; nt < NT; ++nt) {
    const float* xp = x + ((size_t)g * NPTS + n0 + nt * 16 + c) * 3;
    xr[nt][0] = xp[0]; xr[nt][1] = xp[1]; xr[nt][2] = xp[2];
  }

  f32x4 C[4][NT];
  bf16x8 Bh[NT][2], Bl[NT][2];

  // layer 0: x -> 64
  zeroC(C);
  xpart(wgh + 0 * SLOT_ELEMS, wgl + 0 * SLOT_ELEMS, q, c, xr, C);
  cvt_all(C, (const float4*)(b0 + g * 64), q, Bh, Bl);

  // layers 1..4
  zeroC(C); dense(wgh + 1 * SLOT_ELEMS, wgl + 1 * SLOT_ELEMS, q, c, Bh, Bl, C);
  cvt_all(C, (const float4*)(b1 + g * 64), q, Bh, Bl);
  zeroC(C); dense(wgh + 2 * SLOT_ELEMS, wgl + 2 * SLOT_ELEMS, q, c, Bh, Bl, C);
  cvt_all(C, (const float4*)(b2 + g * 64), q, Bh, Bl);
  zeroC(C); dense(wgh + 3 * SLOT_ELEMS, wgl + 3 * SLOT_ELEMS, q, c, Bh, Bl, C);
  cvt_all(C, (const float4*)(b3 + g * 64), q, Bh, Bl);
  zeroC(C); dense(wgh + 4 * SLOT_ELEMS, wgl + 4 * SLOT_ELEMS, q, c, Bh, Bl, C);
  cvt_all(C, (const float4*)(b4 + g * 64), q, Bh, Bl);

  // layer 5: concat([x, h4]) -> x-part (slot 8) + dense h-part (slot 5)
  zeroC(C);
  xpart(wgh + 8 * SLOT_ELEMS, wgl + 8 * SLOT_ELEMS, q, c, xr, C);
  dense(wgh + 5 * SLOT_ELEMS, wgl + 5 * SLOT_ELEMS, q, c, Bh, Bl, C);
  cvt_all(C, (const float4*)(b5 + g * 64), q, Bh, Bl);

  // layers 6..7
  zeroC(C); dense(wgh + 6 * SLOT_ELEMS, wgl + 6 * SLOT_ELEMS, q, c, Bh, Bl, C);
  cvt_all(C, (const float4*)(b6 + g * 64), q, Bh, Bl);
  zeroC(C); dense(wgh + 7 * SLOT_ELEMS, wgl + 7 * SLOT_ELEMS, q, c, Bh, Bl, C);
  cvt_all(C, (const float4*)(b7 + g * 64), q, Bh, Bl);  // leaves relu'd h in C

  // write hfinal (fp32, post-relu, from C; feature = mt*16+q*4+r)
#pragma unroll
  for (int mt = 0; mt < 4; ++mt) {
#pragma unroll
    for (int nt = 0; nt < NT; ++nt) {
      size_t ptg = (size_t)g * NPTS + n0 + nt * 16 + c;
      f32x4 v = C[mt][nt];
      *(float4*)(hfinal + ptg * 64 + mt * 16 + q * 4) = make_float4(v[0], v[1], v[2], v[3]);
    }
  }

  // out layer: 64 -> 4 (slot 9 rows 4..15 zero; result rows 0..3 live in q==0)
  f32x4 Co[NT];
#pragma unroll
  for (int nt = 0; nt < NT; ++nt) {
    f32x4 z = {0.f, 0.f, 0.f, 0.f};
    Co[nt] = z;
  }
#pragma unroll
  for (int kt = 0; kt < 2; ++kt) {
    bf16x8 Ah = *(const bf16x8*)(wgh + 9 * SLOT_ELEMS + c * 64 + kt * 32 + q * 8);
    bf16x8 Al = *(const bf16x8*)(wgl + 9 * SLOT_ELEMS + c * 64 + kt * 32 + q * 8);
#pragma unroll
    for (int nt = 0; nt < NT; ++nt) {
      Co[nt] = __builtin_amdgcn_mfma_f32_16x16x32_bf16(Ah, Bh[nt][kt], Co[nt], 0, 0, 0);
      Co[nt] = __builtin_amdgcn_mfma_f32_16x16x32_bf16(Ah, Bl[nt][kt], Co[nt], 0, 0, 0);
      Co[nt] = __builtin_amdgcn_mfma_f32_16x16x32_bf16(Al, Bh[nt][kt], Co[nt], 0, 0, 0);
    }
  }
  if (q == 0) {
    float4 bo = *(const float4*)(b_out + g * 4);
#pragma unroll
    for (int nt = 0; nt < NT; ++nt) {
      size_t ptg = (size_t)g * NPTS + n0 + nt * 16 + c;
      *(float4*)(out + ptg * 4) =
          make_float4(Co[nt][0] + bo.x, Co[nt][1] + bo.y, Co[nt][2] + bo.z, Co[nt][3] + bo.w);
    }
  }
}

extern "C" void kernel_launch(void* const* d_in, const int* in_sizes, int n_in,
                              void* d_out, int out_size, void* d_ws, size_t ws_size,
                              hipStream_t stream) {
  const float* x  = (const float*)d_in[0];
  const float* w0 = (const float*)d_in[1];  const float* b0 = (const float*)d_in[2];
  const float* w1 = (const float*)d_in[3];  const float* b1 = (const float*)d_in[4];
  const float* w2 = (const float*)d_in[5];  const float* b2 = (const float*)d_in[6];
  const float* w3 = (const float*)d_in[7];  const float* b3 = (const float*)d_in[8];
  const float* w4 = (const float*)d_in[9];  const float* b4 = (const float*)d_in[10];
  const float* w5 = (const float*)d_in[11]; const float* b5 = (const float*)d_in[12];
  const float* w6 = (const float*)d_in[13]; const float* b6 = (const float*)d_in[14];
  const float* w7 = (const float*)d_in[15]; const float* b7 = (const float*)d_in[16];
  const float* w_out = (const float*)d_in[17];
  const float* b_out = (const float*)d_in[18];

  float* out    = (float*)d_out;                          // [G,N,4]
  float* hfinal = (float*)d_out + (size_t)NG * NPTS * 4;  // [G,N,64]

  unsigned short* whi = (unsigned short*)d_ws;
  unsigned short* wlo = whi + WBUF_ELEMS;

  prep_weights<<<dim3((WBUF_ELEMS + 255) / 256), dim3(256), 0, stream>>>(
      w0, w1, w2, w3, w4, w5, w6, w7, w_out, whi, wlo);

  mlp_mfma_kernel<<<dim3(NPTS / 256, NG), dim3(256), 0, stream>>>(
      x, b0, b1, b2, b3, b4, b5, b6, b7, b_out, whi, wlo, out, hfinal);
}